// Round 2
// baseline (199.001 us; speedup 1.0000x reference)
//
#include <hip/hip_runtime.h>
#include <stdint.h>

#define HEADS 12
#define DH 64
#define SEQ 1024
#define BATCH 2
#define DIMC 768
#define MROWS (BATCH*SEQ)   // 2048
#define NQKV (3*DIMC)       // 2304

typedef __bf16 bf16x8 __attribute__((ext_vector_type(8)));
typedef float f32x4 __attribute__((ext_vector_type(4)));
typedef unsigned int u32x4 __attribute__((ext_vector_type(4)));

__device__ __forceinline__ uint16_t f2bf(float f) {
  uint32_t u = __builtin_bit_cast(uint32_t, f);
  uint32_t r = (u + 0x7fffu + ((u >> 16) & 1u)) >> 16;
  return (uint16_t)r;
}
__device__ __forceinline__ float bf2f(uint16_t h) {
  uint32_t u = ((uint32_t)h) << 16;
  return __builtin_bit_cast(float, u);
}

// ---------------- prep: split x into bf16 hi/lo ----------------
__global__ __launch_bounds__(256) void k_split_x(
    const float* __restrict__ x1, const float* __restrict__ x2,
    uint16_t* __restrict__ xh, uint16_t* __restrict__ xl) {
  int i = blockIdx.x * 256 + threadIdx.x;   // float4 index
  const int per = MROWS * DIMC / 4;         // 393216 per stream
  const float* src = (i < per) ? x1 : x2;
  int j = (i < per) ? i : (i - per);
  float4 v = reinterpret_cast<const float4*>(src)[j];
  float f[4] = {v.x, v.y, v.z, v.w};
  uint16_t hh[4], ll[4];
#pragma unroll
  for (int t = 0; t < 4; ++t) {
    hh[t] = f2bf(f[t]);
    ll[t] = f2bf(f[t] - bf2f(hh[t]));
  }
  reinterpret_cast<ushort4*>(xh)[i] = make_ushort4(hh[0], hh[1], hh[2], hh[3]);
  reinterpret_cast<ushort4*>(xl)[i] = make_ushort4(ll[0], ll[1], ll[2], ll[3]);
}

// ---------------- prep: transpose f32 [R][C] -> bf16 [C][R] ----------------
__global__ __launch_bounds__(256) void k_transpose_bf16(
    const float* __restrict__ src, uint16_t* __restrict__ dst, int R, int C) {
  __shared__ uint16_t tile[32][33];
  int c0 = blockIdx.x * 32, r0 = blockIdx.y * 32;
  int tx = threadIdx.x, ty = threadIdx.y;
  for (int rr = ty; rr < 32; rr += 8)
    tile[rr][tx] = f2bf(src[(size_t)(r0 + rr) * C + c0 + tx]);
  __syncthreads();
  for (int rr = ty; rr < 32; rr += 8)
    dst[(size_t)(c0 + rr) * R + r0 + tx] = tile[tx][rr];
}

// ---------------- QKV GEMM: (xh+xl) @ W -> q(*0.125), k, v^T ----------------
__global__ __launch_bounds__(256) void k_qkv_gemm(
    const uint16_t* __restrict__ xh, const uint16_t* __restrict__ xl,
    const uint16_t* __restrict__ wt,   // [2][2304][768] (W transposed)
    uint16_t* __restrict__ qo, uint16_t* __restrict__ ko, uint16_t* __restrict__ vto) {
  __shared__ uint16_t Ah[64][40];
  __shared__ uint16_t Al[64][40];
  __shared__ uint16_t Bt[64][40];
  const int s = blockIdx.z;
  const int m0 = blockIdx.x * 64;
  const int col0 = blockIdx.y * 64;
  const uint16_t* xh_s = xh + (size_t)s * MROWS * DIMC;
  const uint16_t* xl_s = xl + (size_t)s * MROWS * DIMC;
  const uint16_t* wt_s = wt + (size_t)s * NQKV * DIMC;

  const int tid = threadIdx.x;
  const int w = tid >> 6, lane = tid & 63;
  const int wr = w >> 1, wc = w & 1;
  const int lr = lane & 15, lk = (lane >> 4) * 8;
  // staging: 64 rows x 32 cols bf16 = 256 chunks of 8 elems (16 B)
  const int srow = tid >> 2, schunk = (tid & 3) * 8;

  f32x4 acc[2][2] = {};

  for (int k0 = 0; k0 < DIMC; k0 += 32) {
    *reinterpret_cast<u32x4*>(&Ah[srow][schunk]) =
        *reinterpret_cast<const u32x4*>(&xh_s[(size_t)(m0 + srow) * DIMC + k0 + schunk]);
    *reinterpret_cast<u32x4*>(&Al[srow][schunk]) =
        *reinterpret_cast<const u32x4*>(&xl_s[(size_t)(m0 + srow) * DIMC + k0 + schunk]);
    *reinterpret_cast<u32x4*>(&Bt[srow][schunk]) =
        *reinterpret_cast<const u32x4*>(&wt_s[(size_t)(col0 + srow) * DIMC + k0 + schunk]);
    __syncthreads();
    bf16x8 a_h[2], a_l[2], b[2];
#pragma unroll
    for (int f = 0; f < 2; ++f) {
      a_h[f] = *reinterpret_cast<const bf16x8*>(&Ah[wr * 32 + f * 16 + lr][lk]);
      a_l[f] = *reinterpret_cast<const bf16x8*>(&Al[wr * 32 + f * 16 + lr][lk]);
      b[f]   = *reinterpret_cast<const bf16x8*>(&Bt[wc * 32 + f * 16 + lr][lk]);
    }
#pragma unroll
    for (int fm = 0; fm < 2; ++fm)
#pragma unroll
      for (int fn = 0; fn < 2; ++fn) {
        acc[fm][fn] = __builtin_amdgcn_mfma_f32_16x16x32_bf16(a_h[fm], b[fn], acc[fm][fn], 0, 0, 0);
        acc[fm][fn] = __builtin_amdgcn_mfma_f32_16x16x32_bf16(a_l[fm], b[fn], acc[fm][fn], 0, 0, 0);
      }
    __syncthreads();
  }

  const int t = blockIdx.y / 12;   // 0=q, 1=k, 2=v
  const int h = blockIdx.y % 12;
  uint16_t* q_s  = qo  + (size_t)s * 1572864;
  uint16_t* k_s  = ko  + (size_t)s * 1572864;
  uint16_t* vt_s = vto + (size_t)s * 1572864;
#pragma unroll
  for (int fm = 0; fm < 2; ++fm)
#pragma unroll
    for (int fn = 0; fn < 2; ++fn)
#pragma unroll
      for (int i = 0; i < 4; ++i) {
        int m = m0 + wr * 32 + fm * 16 + (lane >> 4) * 4 + i;
        int dh = wc * 32 + fn * 16 + lr;
        int b_ = m >> 10, n = m & 1023;
        float v = acc[fm][fn][i];
        if (t == 0)
          q_s[((size_t)(b_ * HEADS + h) * SEQ + n) * DH + dh] = f2bf(v * 0.125f);
        else if (t == 1)
          k_s[((size_t)(b_ * HEADS + h) * SEQ + n) * DH + dh] = f2bf(v);
        else
          vt_s[((size_t)(b_ * HEADS + h) * DH + dh) * SEQ + n] = f2bf(v);
      }
}

// ---------------- fused dual-pass flash attention ----------------
__global__ __launch_bounds__(256) void k_attn(
    const uint16_t* __restrict__ q, const uint16_t* __restrict__ k,
    const uint16_t* __restrict__ vt, uint16_t* __restrict__ o) {
  __shared__ uint16_t Klds[64][72];
  __shared__ uint16_t Vlds[64][72];
  __shared__ uint16_t Plds[4][16][72];

  int bid = blockIdx.x;
  const int qt = bid & 15;
  int rest = bid >> 4;            // 0..47
  const int h = rest % 12;
  int rest2 = rest / 12;          // 0..3
  const int b = rest2 & 1;
  const int s = rest2 >> 1;

  const int tid = threadIdx.x;
  const int w = tid >> 6, lane = tid & 63;
  const int lr = lane & 15;
  const int hi8 = (lane >> 4) * 8;

  const uint16_t* q_s = q + (size_t)s * 1572864 +
                        ((size_t)(b * HEADS + h) * SEQ + qt * 64 + w * 16 + lr) * DH;
  bf16x8 qf[2];
  qf[0] = *reinterpret_cast<const bf16x8*>(&q_s[hi8]);
  qf[1] = *reinterpret_cast<const bf16x8*>(&q_s[32 + hi8]);

  f32x4 Ofin[4] = {};

  for (int pass = 0; pass < 2; ++pass) {
    const int ks = (pass == 0) ? s : 1 - s;
    const uint16_t* kbase = k  + (size_t)ks * 1572864 + (size_t)(b * HEADS + h) * SEQ * DH;
    const uint16_t* vbase = vt + (size_t)ks * 1572864 + (size_t)(b * HEADS + h) * DH * SEQ;

    f32x4 Oacc[4] = {};
    float mrow[4], lrow[4];
#pragma unroll
    for (int i = 0; i < 4; ++i) { mrow[i] = -1e30f; lrow[i] = 0.f; }

    for (int kt = 0; kt < 16; ++kt) {
#pragma unroll
      for (int c = 0; c < 2; ++c) {
        int cc = tid + c * 256;
        int row = cc >> 3, chunk = (cc & 7) * 8;
        *reinterpret_cast<u32x4*>(&Klds[row][chunk]) =
            *reinterpret_cast<const u32x4*>(&kbase[(size_t)(kt * 64 + row) * DH + chunk]);
        *reinterpret_cast<u32x4*>(&Vlds[row][chunk]) =
            *reinterpret_cast<const u32x4*>(&vbase[(size_t)row * SEQ + kt * 64 + chunk]);
      }
      __syncthreads();

      f32x4 S[4];
#pragma unroll
      for (int fn = 0; fn < 4; ++fn) {
        bf16x8 kb0 = *reinterpret_cast<const bf16x8*>(&Klds[fn * 16 + lr][hi8]);
        bf16x8 kb1 = *reinterpret_cast<const bf16x8*>(&Klds[fn * 16 + lr][32 + hi8]);
        f32x4 z = {};
        z = __builtin_amdgcn_mfma_f32_16x16x32_bf16(qf[0], kb0, z, 0, 0, 0);
        S[fn] = __builtin_amdgcn_mfma_f32_16x16x32_bf16(qf[1], kb1, z, 0, 0, 0);
      }

#pragma unroll
      for (int i = 0; i < 4; ++i) {
        float tmax = fmaxf(fmaxf(S[0][i], S[1][i]), fmaxf(S[2][i], S[3][i]));
        tmax = fmaxf(tmax, __shfl_xor(tmax, 1));
        tmax = fmaxf(tmax, __shfl_xor(tmax, 2));
        tmax = fmaxf(tmax, __shfl_xor(tmax, 4));
        tmax = fmaxf(tmax, __shfl_xor(tmax, 8));
        float mnew = fmaxf(mrow[i], tmax);
        float alpha = __expf(mrow[i] - mnew);
        mrow[i] = mnew;
        float rs = 0.f;
#pragma unroll
        for (int fn = 0; fn < 4; ++fn) {
          float p = __expf(S[fn][i] - mnew);
          S[fn][i] = p;
          rs += p;
        }
        rs += __shfl_xor(rs, 1);
        rs += __shfl_xor(rs, 2);
        rs += __shfl_xor(rs, 4);
        rs += __shfl_xor(rs, 8);
        lrow[i] = lrow[i] * alpha + rs;
#pragma unroll
        for (int fn = 0; fn < 4; ++fn) Oacc[fn][i] *= alpha;
        int prow = (lane >> 4) * 4 + i;
#pragma unroll
        for (int fn = 0; fn < 4; ++fn)
          Plds[w][prow][fn * 16 + lr] = f2bf(S[fn][i]);
      }

      // PV (P written+read by the same wave: no barrier needed)
      bf16x8 pa0 = *reinterpret_cast<const bf16x8*>(&Plds[w][lr][hi8]);
      bf16x8 pa1 = *reinterpret_cast<const bf16x8*>(&Plds[w][lr][32 + hi8]);
#pragma unroll
      for (int fn = 0; fn < 4; ++fn) {
        bf16x8 vb0 = *reinterpret_cast<const bf16x8*>(&Vlds[fn * 16 + lr][hi8]);
        bf16x8 vb1 = *reinterpret_cast<const bf16x8*>(&Vlds[fn * 16 + lr][32 + hi8]);
        Oacc[fn] = __builtin_amdgcn_mfma_f32_16x16x32_bf16(pa0, vb0, Oacc[fn], 0, 0, 0);
        Oacc[fn] = __builtin_amdgcn_mfma_f32_16x16x32_bf16(pa1, vb1, Oacc[fn], 0, 0, 0);
      }
      __syncthreads();
    }

#pragma unroll
    for (int i = 0; i < 4; ++i) {
      float inv = 1.f / lrow[i];
#pragma unroll
      for (int fn = 0; fn < 4; ++fn) Ofin[fn][i] += Oacc[fn][i] * inv;
    }
  }

  uint16_t* o_s = o + (size_t)s * MROWS * DIMC;
#pragma unroll
  for (int fn = 0; fn < 4; ++fn)
#pragma unroll
    for (int i = 0; i < 4; ++i) {
      int n = qt * 64 + w * 16 + (lane >> 4) * 4 + i;
      int col = h * 64 + fn * 16 + lr;
      o_s[(size_t)(b * SEQ + n) * DIMC + col] = f2bf(Ofin[fn][i]);
    }
}

// ---------------- projection GEMM: o @ Wp + bias -> f32 out ----------------
__global__ __launch_bounds__(256) void k_proj_gemm(
    const uint16_t* __restrict__ o, const uint16_t* __restrict__ wpt,
    const float* __restrict__ bp1, const float* __restrict__ bp2,
    float* __restrict__ out) {
  __shared__ uint16_t At[64][40];
  __shared__ uint16_t Bt[64][40];
  const int s = blockIdx.z;
  const int m0 = blockIdx.x * 64;
  const int col0 = blockIdx.y * 64;
  const uint16_t* o_s = o + (size_t)s * MROWS * DIMC;
  const uint16_t* w_s = wpt + (size_t)s * DIMC * DIMC;
  const float* bias = (s == 0) ? bp1 : bp2;
  float* out_s = out + (size_t)s * MROWS * DIMC;

  const int tid = threadIdx.x;
  const int w = tid >> 6, lane = tid & 63;
  const int wr = w >> 1, wc = w & 1;
  const int lr = lane & 15, lk = (lane >> 4) * 8;
  const int srow = tid >> 2, schunk = (tid & 3) * 8;

  f32x4 acc[2][2] = {};

  for (int k0 = 0; k0 < DIMC; k0 += 32) {
    *reinterpret_cast<u32x4*>(&At[srow][schunk]) =
        *reinterpret_cast<const u32x4*>(&o_s[(size_t)(m0 + srow) * DIMC + k0 + schunk]);
    *reinterpret_cast<u32x4*>(&Bt[srow][schunk]) =
        *reinterpret_cast<const u32x4*>(&w_s[(size_t)(col0 + srow) * DIMC + k0 + schunk]);
    __syncthreads();
    bf16x8 a[2], bfr[2];
#pragma unroll
    for (int f = 0; f < 2; ++f) {
      a[f]   = *reinterpret_cast<const bf16x8*>(&At[wr * 32 + f * 16 + lr][lk]);
      bfr[f] = *reinterpret_cast<const bf16x8*>(&Bt[wc * 32 + f * 16 + lr][lk]);
    }
#pragma unroll
    for (int fm = 0; fm < 2; ++fm)
#pragma unroll
      for (int fn = 0; fn < 2; ++fn)
        acc[fm][fn] = __builtin_amdgcn_mfma_f32_16x16x32_bf16(a[fm], bfr[fn], acc[fm][fn], 0, 0, 0);
    __syncthreads();
  }

#pragma unroll
  for (int fm = 0; fm < 2; ++fm)
#pragma unroll
    for (int fn = 0; fn < 2; ++fn)
#pragma unroll
      for (int i = 0; i < 4; ++i) {
        int m = m0 + wr * 32 + fm * 16 + (lane >> 4) * 4 + i;
        int col = col0 + wc * 32 + fn * 16 + lr;
        out_s[(size_t)m * DIMC + col] = acc[fm][fn][i] + bias[col];
      }
}

extern "C" void kernel_launch(void* const* d_in, const int* in_sizes, int n_in,
                              void* d_out, int out_size, void* d_ws, size_t ws_size,
                              hipStream_t stream) {
  const float* x1    = (const float*)d_in[0];
  const float* x2    = (const float*)d_in[1];
  const float* Wqkv1 = (const float*)d_in[2];
  const float* Wqkv2 = (const float*)d_in[3];
  const float* Wp1   = (const float*)d_in[4];
  const float* bp1   = (const float*)d_in[5];
  const float* Wp2   = (const float*)d_in[6];
  const float* bp2   = (const float*)d_in[7];
  float* out = (float*)d_out;

  uint8_t* ws = (uint8_t*)d_ws;
  uint16_t* xh    = (uint16_t*)(ws);             // 2*2048*768 bf16 = 6291456 B
  uint16_t* xl    = (uint16_t*)(ws + 6291456);
  uint16_t* wqkvt = (uint16_t*)(ws + 12582912);  // 2*2304*768 = 7077888 B
  uint16_t* wpt   = (uint16_t*)(ws + 19660800);  // 2*768*768  = 2359296 B
  uint16_t* qb    = (uint16_t*)(ws + 22020096);  // 2*1572864  = 6291456 B
  uint16_t* kb    = (uint16_t*)(ws + 28311552);
  uint16_t* vtb   = (uint16_t*)(ws + 34603008);
  uint16_t* ob    = (uint16_t*)(ws + 40894464);  // total 47185920 B

  k_split_x<<<3072, 256, 0, stream>>>(x1, x2, xh, xl);
  k_transpose_bf16<<<dim3(72, 24), dim3(32, 8), 0, stream>>>(Wqkv1, wqkvt, 768, 2304);
  k_transpose_bf16<<<dim3(72, 24), dim3(32, 8), 0, stream>>>(Wqkv2, wqkvt + 2304 * 768, 768, 2304);
  k_transpose_bf16<<<dim3(24, 24), dim3(32, 8), 0, stream>>>(Wp1, wpt, 768, 768);
  k_transpose_bf16<<<dim3(24, 24), dim3(32, 8), 0, stream>>>(Wp2, wpt + 768 * 768, 768, 768);
  k_qkv_gemm<<<dim3(32, 36, 2), 256, 0, stream>>>(xh, xl, wqkvt, qb, kb, vtb);
  k_attn<<<768, 256, 0, stream>>>(qb, kb, vtb, ob);
  k_proj_gemm<<<dim3(32, 12, 2), 256, 0, stream>>>(ob, wpt, bp1, bp2, out);
}

// Round 3
// 150.514 us; speedup vs baseline: 1.3221x; 1.3221x over previous
//
#include <hip/hip_runtime.h>
#include <stdint.h>

#define HEADS 12
#define DH 64
#define SEQ 1024
#define BATCH 2
#define DIMC 768
#define MROWS (BATCH*SEQ)   // 2048
#define NQKV (3*DIMC)       // 2304

typedef __bf16 bf16x8 __attribute__((ext_vector_type(8)));
typedef float f32x4 __attribute__((ext_vector_type(4)));
typedef unsigned int u32x4 __attribute__((ext_vector_type(4)));

__device__ __forceinline__ uint16_t f2bf(float f) {
  uint32_t u = __builtin_bit_cast(uint32_t, f);
  uint32_t r = (u + 0x7fffu + ((u >> 16) & 1u)) >> 16;
  return (uint16_t)r;
}
__device__ __forceinline__ float bf2f(uint16_t h) {
  uint32_t u = ((uint32_t)h) << 16;
  return __builtin_bit_cast(float, u);
}

// ---------------- prep: split x into bf16 hi/lo ----------------
__global__ __launch_bounds__(256) void k_split_x(
    const float* __restrict__ x1, const float* __restrict__ x2,
    uint16_t* __restrict__ xh, uint16_t* __restrict__ xl) {
  int i = blockIdx.x * 256 + threadIdx.x;   // float4 index
  const int per = MROWS * DIMC / 4;         // 393216 per stream
  const float* src = (i < per) ? x1 : x2;
  int j = (i < per) ? i : (i - per);
  float4 v = reinterpret_cast<const float4*>(src)[j];
  float f[4] = {v.x, v.y, v.z, v.w};
  uint16_t hh[4], ll[4];
#pragma unroll
  for (int t = 0; t < 4; ++t) {
    hh[t] = f2bf(f[t]);
    ll[t] = f2bf(f[t] - bf2f(hh[t]));
  }
  reinterpret_cast<ushort4*>(xh)[i] = make_ushort4(hh[0], hh[1], hh[2], hh[3]);
  reinterpret_cast<ushort4*>(xl)[i] = make_ushort4(ll[0], ll[1], ll[2], ll[3]);
}

// ---------------- prep: transpose f32 [R][C] -> bf16 [C][R] ----------------
__global__ __launch_bounds__(256) void k_transpose_bf16(
    const float* __restrict__ src, uint16_t* __restrict__ dst, int R, int C) {
  __shared__ uint16_t tile[32][33];
  int c0 = blockIdx.x * 32, r0 = blockIdx.y * 32;
  int tx = threadIdx.x, ty = threadIdx.y;
  for (int rr = ty; rr < 32; rr += 8)
    tile[rr][tx] = f2bf(src[(size_t)(r0 + rr) * C + c0 + tx]);
  __syncthreads();
  for (int rr = ty; rr < 32; rr += 8)
    dst[(size_t)(c0 + rr) * R + r0 + tx] = tile[tx][rr];
}

// ---------------- QKV GEMM: (xh+xl) @ W -> q(*0.125), k, v^T ----------------
__global__ __launch_bounds__(256) void k_qkv_gemm(
    const uint16_t* __restrict__ xh, const uint16_t* __restrict__ xl,
    const uint16_t* __restrict__ wt,   // [2][2304][768] (W transposed)
    uint16_t* __restrict__ qo, uint16_t* __restrict__ ko, uint16_t* __restrict__ vto) {
  __shared__ uint16_t Ah[64][40];
  __shared__ uint16_t Al[64][40];
  __shared__ uint16_t Bt[64][40];
  const int s = blockIdx.z;
  const int m0 = blockIdx.x * 64;
  const int col0 = blockIdx.y * 64;
  const uint16_t* xh_s = xh + (size_t)s * MROWS * DIMC;
  const uint16_t* xl_s = xl + (size_t)s * MROWS * DIMC;
  const uint16_t* wt_s = wt + (size_t)s * NQKV * DIMC;

  const int tid = threadIdx.x;
  const int w = tid >> 6, lane = tid & 63;
  const int wr = w >> 1, wc = w & 1;
  const int lr = lane & 15, lk = (lane >> 4) * 8;
  const int srow = tid >> 2, schunk = (tid & 3) * 8;

  f32x4 acc[2][2] = {};

  for (int k0 = 0; k0 < DIMC; k0 += 32) {
    *reinterpret_cast<u32x4*>(&Ah[srow][schunk]) =
        *reinterpret_cast<const u32x4*>(&xh_s[(size_t)(m0 + srow) * DIMC + k0 + schunk]);
    *reinterpret_cast<u32x4*>(&Al[srow][schunk]) =
        *reinterpret_cast<const u32x4*>(&xl_s[(size_t)(m0 + srow) * DIMC + k0 + schunk]);
    *reinterpret_cast<u32x4*>(&Bt[srow][schunk]) =
        *reinterpret_cast<const u32x4*>(&wt_s[(size_t)(col0 + srow) * DIMC + k0 + schunk]);
    __syncthreads();
    bf16x8 a_h[2], a_l[2], b[2];
#pragma unroll
    for (int f = 0; f < 2; ++f) {
      a_h[f] = *reinterpret_cast<const bf16x8*>(&Ah[wr * 32 + f * 16 + lr][lk]);
      a_l[f] = *reinterpret_cast<const bf16x8*>(&Al[wr * 32 + f * 16 + lr][lk]);
      b[f]   = *reinterpret_cast<const bf16x8*>(&Bt[wc * 32 + f * 16 + lr][lk]);
    }
#pragma unroll
    for (int fm = 0; fm < 2; ++fm)
#pragma unroll
      for (int fn = 0; fn < 2; ++fn) {
        acc[fm][fn] = __builtin_amdgcn_mfma_f32_16x16x32_bf16(a_h[fm], b[fn], acc[fm][fn], 0, 0, 0);
        acc[fm][fn] = __builtin_amdgcn_mfma_f32_16x16x32_bf16(a_l[fm], b[fn], acc[fm][fn], 0, 0, 0);
      }
    __syncthreads();
  }

  const int t = blockIdx.y / 12;   // 0=q, 1=k, 2=v
  const int h = blockIdx.y % 12;
  uint16_t* q_s  = qo  + (size_t)s * 1572864;
  uint16_t* k_s  = ko  + (size_t)s * 1572864;
  uint16_t* vt_s = vto + (size_t)s * 1572864;
#pragma unroll
  for (int fm = 0; fm < 2; ++fm)
#pragma unroll
    for (int fn = 0; fn < 2; ++fn)
#pragma unroll
      for (int i = 0; i < 4; ++i) {
        int m = m0 + wr * 32 + fm * 16 + (lane >> 4) * 4 + i;
        int dh = wc * 32 + fn * 16 + lr;
        int b_ = m >> 10, n = m & 1023;
        float v = acc[fm][fn][i];
        if (t == 0)
          q_s[((size_t)(b_ * HEADS + h) * SEQ + n) * DH + dh] = f2bf(v * 0.125f);
        else if (t == 1)
          k_s[((size_t)(b_ * HEADS + h) * SEQ + n) * DH + dh] = f2bf(v);
        else
          vt_s[((size_t)(b_ * HEADS + h) * DH + dh) * SEQ + n] = f2bf(v);
      }
}

// ---------------- fused dual-pass flash attention (swapped QK^T) ----------------
// S^T = mfma(K, Q): each lane owns one q-row (lr), 16 of 64 keys in-lane.
// K rows permuted per-mfma so lane g's keys are {8g..8g+7, 32+8g..32+8g+7}
// -> P feeds PV's A-fragment in natural slot order (zero shuffles, no P LDS).
__global__ __launch_bounds__(256) void k_attn(
    const uint16_t* __restrict__ q, const uint16_t* __restrict__ k,
    const uint16_t* __restrict__ vt, uint16_t* __restrict__ o) {
  __shared__ uint16_t Klds[64][64];   // [key][dh], col chunks XOR-swizzled by row&7
  __shared__ uint16_t Vlds[64][64];   // [dh][key], col chunks XOR-swizzled by row&7

  // XCD-contiguous remap (768 = 8 XCDs * 96 blocks; bijective since 768%8==0)
  int bid = blockIdx.x;
  bid = (bid & 7) * 96 + (bid >> 3);
  const int qt = bid & 15;
  int rest = bid >> 4;            // 0..47
  const int h = rest % 12;
  int rest2 = rest / 12;          // 0..3
  const int b = rest2 & 1;
  const int s = rest2 >> 1;

  const int tid = threadIdx.x;
  const int w = tid >> 6, lane = tid & 63;
  const int lr = lane & 15;
  const int g = lane >> 4;        // 0..3
  const int hi8 = g * 8;

  // Q fragment (B operand): col = q-row = w*16+lr
  const uint16_t* q_s = q + (size_t)s * 1572864 +
                        ((size_t)(b * HEADS + h) * SEQ + qt * 64 + w * 16 + lr) * DH;
  const bf16x8 qf0 = *reinterpret_cast<const bf16x8*>(&q_s[hi8]);
  const bf16x8 qf1 = *reinterpret_cast<const bf16x8*>(&q_s[32 + hi8]);

  // permuted K row base: A-row lr of block fn holds key klo + 4*(fn&1) + 32*(fn>>1)
  const int klo = (lr >> 2) * 8 + (lr & 3);

  // staging slots: 64 rows x 8 chunks(16B) per tile, 2 slots/thread/tile
  const int r0 = tid >> 3;                 // 0..31 (and r0+32)
  const int c0 = tid & 7;
  const int swc = 8 * (c0 ^ (r0 & 7));     // (r0+32)&7 == r0&7

  const uint16_t* kbase0 = k  + (size_t)s * 1572864 + (size_t)(b * HEADS + h) * SEQ * DH;
  const uint16_t* vbase0 = vt + (size_t)s * 1572864 + (size_t)(b * HEADS + h) * DH * SEQ;
  const uint16_t* kbase1 = k  + (size_t)(1 - s) * 1572864 + (size_t)(b * HEADS + h) * SEQ * DH;
  const uint16_t* vbase1 = vt + (size_t)(1 - s) * 1572864 + (size_t)(b * HEADS + h) * DH * SEQ;

  u32x4 kr0, kr1, vr0, vr1;

#define LOADT(T) { const int tt = (T); const int kt_ = tt & 15;                             \
    const uint16_t* kp = (tt >= 16) ? kbase1 : kbase0;                                      \
    const uint16_t* vp = (tt >= 16) ? vbase1 : vbase0;                                      \
    kr0 = *reinterpret_cast<const u32x4*>(&kp[(size_t)(kt_ * 64 + r0) * DH + c0 * 8]);      \
    kr1 = *reinterpret_cast<const u32x4*>(&kp[(size_t)(kt_ * 64 + r0 + 32) * DH + c0 * 8]); \
    vr0 = *reinterpret_cast<const u32x4*>(&vp[(size_t)r0 * SEQ + kt_ * 64 + c0 * 8]);       \
    vr1 = *reinterpret_cast<const u32x4*>(&vp[(size_t)(r0 + 32) * SEQ + kt_ * 64 + c0 * 8]); }

#define STORET() {                                            \
    *reinterpret_cast<u32x4*>(&Klds[r0][swc]) = kr0;          \
    *reinterpret_cast<u32x4*>(&Klds[r0 + 32][swc]) = kr1;     \
    *reinterpret_cast<u32x4*>(&Vlds[r0][swc]) = vr0;          \
    *reinterpret_cast<u32x4*>(&Vlds[r0 + 32][swc]) = vr1; }

  LOADT(0);
  STORET();
  __syncthreads();

  f32x4 Oacc[4] = {};
  f32x4 Ofin[4] = {};
  float mrow = -1e30f, lrow = 0.f;

  for (int t = 0; t < 32; ++t) {
    if (t < 31) LOADT(t + 1);   // issue-early; vmcnt waited only at STORET

    // ---- S^T = K @ Q (4 fn-blocks of 16 permuted keys) ----
    f32x4 S[4];
#pragma unroll
    for (int fn = 0; fn < 4; ++fn) {
      const int krow = klo + 4 * (fn & 1) + 32 * (fn >> 1);
      const int sw = krow & 7;
      bf16x8 ka = *reinterpret_cast<const bf16x8*>(&Klds[krow][8 * (g ^ sw)]);
      bf16x8 kb = *reinterpret_cast<const bf16x8*>(&Klds[krow][8 * ((4 + g) ^ sw)]);
      f32x4 z = {};
      z = __builtin_amdgcn_mfma_f32_16x16x32_bf16(ka, qf0, z, 0, 0, 0);
      S[fn] = __builtin_amdgcn_mfma_f32_16x16x32_bf16(kb, qf1, z, 0, 0, 0);
    }

    // ---- in-register online softmax (per-lane q-row) ----
    float vmax = fmaxf(fmaxf(fmaxf(S[0][0], S[0][1]), fmaxf(S[0][2], S[0][3])),
                       fmaxf(fmaxf(S[1][0], S[1][1]), fmaxf(S[1][2], S[1][3])));
    vmax = fmaxf(vmax, fmaxf(fmaxf(fmaxf(S[2][0], S[2][1]), fmaxf(S[2][2], S[2][3])),
                             fmaxf(fmaxf(S[3][0], S[3][1]), fmaxf(S[3][2], S[3][3]))));
    vmax = fmaxf(vmax, __shfl_xor(vmax, 16));
    vmax = fmaxf(vmax, __shfl_xor(vmax, 32));
    const float mnew = fmaxf(mrow, vmax);
    const float alpha = __expf(mrow - mnew);
    mrow = mnew;
    float rs = 0.f;
#pragma unroll
    for (int fn = 0; fn < 4; ++fn)
#pragma unroll
      for (int i = 0; i < 4; ++i) {
        float p = __expf(S[fn][i] - mnew);
        S[fn][i] = p;
        rs += p;
      }
    rs += __shfl_xor(rs, 16);
    rs += __shfl_xor(rs, 32);
    lrow = lrow * alpha + rs;

    // pack P -> bf16 A-fragments (natural slot order, keys 8g+j / 32+8g+j)
    bf16x8 pa0, pa1;
#pragma unroll
    for (int i = 0; i < 4; ++i) {
      pa0[i]     = (__bf16)S[0][i];
      pa0[4 + i] = (__bf16)S[1][i];
      pa1[i]     = (__bf16)S[2][i];
      pa1[4 + i] = (__bf16)S[3][i];
    }

    // broadcast alpha for output rows 4g+i (held by lane 20g+i) and rescale O
    float af[4];
#pragma unroll
    for (int i = 0; i < 4; ++i) af[i] = __shfl(alpha, 20 * g + i);
#pragma unroll
    for (int fn = 0; fn < 4; ++fn)
#pragma unroll
      for (int i = 0; i < 4; ++i) Oacc[fn][i] *= af[i];

    // ---- PV ----
#pragma unroll
    for (int fn = 0; fn < 4; ++fn) {
      const int vrow = fn * 16 + lr;
      const int sw = vrow & 7;
      bf16x8 va = *reinterpret_cast<const bf16x8*>(&Vlds[vrow][8 * (g ^ sw)]);
      bf16x8 vb = *reinterpret_cast<const bf16x8*>(&Vlds[vrow][8 * ((4 + g) ^ sw)]);
      Oacc[fn] = __builtin_amdgcn_mfma_f32_16x16x32_bf16(pa0, va, Oacc[fn], 0, 0, 0);
      Oacc[fn] = __builtin_amdgcn_mfma_f32_16x16x32_bf16(pa1, vb, Oacc[fn], 0, 0, 0);
    }

    // ---- pass epilogue ----
    if (t == 15 || t == 31) {
      const float linv = 1.f / lrow;
      float li[4];
#pragma unroll
      for (int i = 0; i < 4; ++i) li[i] = __shfl(linv, 20 * g + i);
#pragma unroll
      for (int fn = 0; fn < 4; ++fn)
#pragma unroll
        for (int i = 0; i < 4; ++i) Ofin[fn][i] += Oacc[fn][i] * li[i];
      if (t == 15) {
        mrow = -1e30f; lrow = 0.f;
#pragma unroll
        for (int fn = 0; fn < 4; ++fn) Oacc[fn] = f32x4{};
      }
    }

    __syncthreads();
    if (t < 31) {
      STORET();   // compiler inserts vmcnt wait on kr/vr here
      __syncthreads();
    }
  }
#undef LOADT
#undef STORET

  uint16_t* o_s = o + (size_t)s * MROWS * DIMC;
#pragma unroll
  for (int fn = 0; fn < 4; ++fn)
#pragma unroll
    for (int i = 0; i < 4; ++i) {
      int n = qt * 64 + w * 16 + g * 4 + i;
      int col = h * 64 + fn * 16 + lr;
      o_s[(size_t)(b * SEQ + n) * DIMC + col] = f2bf(Ofin[fn][i]);
    }
}

// ---------------- projection GEMM: o @ Wp + bias -> f32 out ----------------
__global__ __launch_bounds__(256) void k_proj_gemm(
    const uint16_t* __restrict__ o, const uint16_t* __restrict__ wpt,
    const float* __restrict__ bp1, const float* __restrict__ bp2,
    float* __restrict__ out) {
  __shared__ uint16_t At[64][40];
  __shared__ uint16_t Bt[64][40];
  const int s = blockIdx.z;
  const int m0 = blockIdx.x * 64;
  const int col0 = blockIdx.y * 64;
  const uint16_t* o_s = o + (size_t)s * MROWS * DIMC;
  const uint16_t* w_s = wpt + (size_t)s * DIMC * DIMC;
  const float* bias = (s == 0) ? bp1 : bp2;
  float* out_s = out + (size_t)s * MROWS * DIMC;

  const int tid = threadIdx.x;
  const int w = tid >> 6, lane = tid & 63;
  const int wr = w >> 1, wc = w & 1;
  const int lr = lane & 15, lk = (lane >> 4) * 8;
  const int srow = tid >> 2, schunk = (tid & 3) * 8;

  f32x4 acc[2][2] = {};

  for (int k0 = 0; k0 < DIMC; k0 += 32) {
    *reinterpret_cast<u32x4*>(&At[srow][schunk]) =
        *reinterpret_cast<const u32x4*>(&o_s[(size_t)(m0 + srow) * DIMC + k0 + schunk]);
    *reinterpret_cast<u32x4*>(&Bt[srow][schunk]) =
        *reinterpret_cast<const u32x4*>(&w_s[(size_t)(col0 + srow) * DIMC + k0 + schunk]);
    __syncthreads();
    bf16x8 a[2], bfr[2];
#pragma unroll
    for (int f = 0; f < 2; ++f) {
      a[f]   = *reinterpret_cast<const bf16x8*>(&At[wr * 32 + f * 16 + lr][lk]);
      bfr[f] = *reinterpret_cast<const bf16x8*>(&Bt[wc * 32 + f * 16 + lr][lk]);
    }
#pragma unroll
    for (int fm = 0; fm < 2; ++fm)
#pragma unroll
      for (int fn = 0; fn < 2; ++fn)
        acc[fm][fn] = __builtin_amdgcn_mfma_f32_16x16x32_bf16(a[fm], bfr[fn], acc[fm][fn], 0, 0, 0);
    __syncthreads();
  }

#pragma unroll
  for (int fm = 0; fm < 2; ++fm)
#pragma unroll
    for (int fn = 0; fn < 2; ++fn)
#pragma unroll
      for (int i = 0; i < 4; ++i) {
        int m = m0 + wr * 32 + fm * 16 + (lane >> 4) * 4 + i;
        int col = col0 + wc * 32 + fn * 16 + lr;
        out_s[(size_t)m * DIMC + col] = acc[fm][fn][i] + bias[col];
      }
}

extern "C" void kernel_launch(void* const* d_in, const int* in_sizes, int n_in,
                              void* d_out, int out_size, void* d_ws, size_t ws_size,
                              hipStream_t stream) {
  const float* x1    = (const float*)d_in[0];
  const float* x2    = (const float*)d_in[1];
  const float* Wqkv1 = (const float*)d_in[2];
  const float* Wqkv2 = (const float*)d_in[3];
  const float* Wp1   = (const float*)d_in[4];
  const float* bp1   = (const float*)d_in[5];
  const float* Wp2   = (const float*)d_in[6];
  const float* bp2   = (const float*)d_in[7];
  float* out = (float*)d_out;

  uint8_t* ws = (uint8_t*)d_ws;
  uint16_t* xh    = (uint16_t*)(ws);             // 2*2048*768 bf16 = 6291456 B
  uint16_t* xl    = (uint16_t*)(ws + 6291456);
  uint16_t* wqkvt = (uint16_t*)(ws + 12582912);  // 2*2304*768 = 7077888 B
  uint16_t* wpt   = (uint16_t*)(ws + 19660800);  // 2*768*768  = 2359296 B
  uint16_t* qb    = (uint16_t*)(ws + 22020096);  // 2*1572864  = 6291456 B
  uint16_t* kb    = (uint16_t*)(ws + 28311552);
  uint16_t* vtb   = (uint16_t*)(ws + 34603008);
  uint16_t* ob    = (uint16_t*)(ws + 40894464);  // total 47185920 B

  k_split_x<<<3072, 256, 0, stream>>>(x1, x2, xh, xl);
  k_transpose_bf16<<<dim3(72, 24), dim3(32, 8), 0, stream>>>(Wqkv1, wqkvt, 768, 2304);
  k_transpose_bf16<<<dim3(72, 24), dim3(32, 8), 0, stream>>>(Wqkv2, wqkvt + 2304 * 768, 768, 2304);
  k_transpose_bf16<<<dim3(24, 24), dim3(32, 8), 0, stream>>>(Wp1, wpt, 768, 768);
  k_transpose_bf16<<<dim3(24, 24), dim3(32, 8), 0, stream>>>(Wp2, wpt + 768 * 768, 768, 768);
  k_qkv_gemm<<<dim3(32, 36, 2), 256, 0, stream>>>(xh, xl, wqkvt, qb, kb, vtb);
  k_attn<<<768, 256, 0, stream>>>(qb, kb, vtb, ob);
  k_proj_gemm<<<dim3(32, 12, 2), 256, 0, stream>>>(ob, wpt, bp1, bp2, out);
}